// Round 2
// baseline (39488.132 us; speedup 1.0000x reference)
//
#include <hip/hip_runtime.h>

#define NUM_FEATURES 1024
#define NUM_TRAINING 32768
#define NUM_EPOCHS 2
#define STEP_SIZE 0.01f

// Single-wave sequential SGD.
// Layout: lane L owns features { j*256 + L*4 + t : j in [0,4), t in [0,4) }.
// Each lane keeps its 16 theta values in registers (4x float4). Per sample:
//   - x row (4 KB) loaded as 4 coalesced float4 per lane, PREFETCHED one
//     sample ahead (loads don't depend on theta -> fully off critical path)
//   - dot: 4 independent FMA chains of 4, then 2 add levels (~36 cy)
//   - 64-lane butterfly reduce via __shfl_xor (6 dependent shuffles)
//   - sigmoid via v_exp_f32 (exp2) + v_rcp_f32
//   - theta axpy (16 FMAs)
// No LDS, no barriers: the whole 65536-step chain runs at register/shuffle
// latency on one wave.
__global__ __launch_bounds__(64, 1) void sgd_seq_kernel(
    const float* __restrict__ data,
    const float* __restrict__ label,
    const float* __restrict__ theta_in,
    float* __restrict__ theta_out)
{
    const int lane = threadIdx.x;  // 0..63

    const float4* data4  = (const float4*)data;       // row stride = 256 float4
    const float4* th4_in = (const float4*)theta_in;

    float4 th[4];
#pragma unroll
    for (int j = 0; j < 4; ++j) th[j] = th4_in[j * 64 + lane];

    // Prefetch sample 0
    float4 xv[4], xn[4];
#pragma unroll
    for (int j = 0; j < 4; ++j) xv[j] = data4[j * 64 + lane];
    float y = label[0];

    const int total = NUM_EPOCHS * NUM_TRAINING;
    for (int it = 0; it < total; ++it) {
        // ---- prefetch next sample (independent of theta) ----
        int nn = it + 1;
        int nidx = (nn >= total) ? 0 : (nn & (NUM_TRAINING - 1));
        const float4* xp = data4 + (size_t)nidx * (NUM_FEATURES / 4);
#pragma unroll
        for (int j = 0; j < 4; ++j) xn[j] = xp[j * 64 + lane];
        float ynext = label[nidx];

        // ---- per-lane partial dot: 4 independent chains of 4 FMAs ----
        float p0 = xv[0].x * th[0].x;
        p0 = fmaf(xv[0].y, th[0].y, p0);
        p0 = fmaf(xv[0].z, th[0].z, p0);
        p0 = fmaf(xv[0].w, th[0].w, p0);
        float p1 = xv[1].x * th[1].x;
        p1 = fmaf(xv[1].y, th[1].y, p1);
        p1 = fmaf(xv[1].z, th[1].z, p1);
        p1 = fmaf(xv[1].w, th[1].w, p1);
        float p2 = xv[2].x * th[2].x;
        p2 = fmaf(xv[2].y, th[2].y, p2);
        p2 = fmaf(xv[2].z, th[2].z, p2);
        p2 = fmaf(xv[2].w, th[2].w, p2);
        float p3 = xv[3].x * th[3].x;
        p3 = fmaf(xv[3].y, th[3].y, p3);
        p3 = fmaf(xv[3].z, th[3].z, p3);
        p3 = fmaf(xv[3].w, th[3].w, p3);
        float p = (p0 + p1) + (p2 + p3);

        // ---- 64-lane butterfly reduction (all lanes end with total) ----
#pragma unroll
        for (int off = 32; off > 0; off >>= 1)
            p += __shfl_xor(p, off, 64);

        // ---- sigmoid + step coefficient ----
        // sigmoid(p) = 1/(1+exp(-p)); v_exp_f32 computes 2^x, so feed -p*log2(e)
        float e = __builtin_amdgcn_exp2f(-p * 1.44269504088896340736f);  // exp(-p)
        float prob = __builtin_amdgcn_rcpf(1.0f + e);
        float c = STEP_SIZE * (prob - y);

        // ---- theta update (16 FMAs) ----
#pragma unroll
        for (int j = 0; j < 4; ++j) {
            th[j].x = fmaf(-c, xv[j].x, th[j].x);
            th[j].y = fmaf(-c, xv[j].y, th[j].y);
            th[j].z = fmaf(-c, xv[j].z, th[j].z);
            th[j].w = fmaf(-c, xv[j].w, th[j].w);
        }

        // rotate prefetch buffers
#pragma unroll
        for (int j = 0; j < 4; ++j) xv[j] = xn[j];
        y = ynext;
    }

    float4* out4 = (float4*)theta_out;
#pragma unroll
    for (int j = 0; j < 4; ++j) out4[j * 64 + lane] = th[j];
}

extern "C" void kernel_launch(void* const* d_in, const int* in_sizes, int n_in,
                              void* d_out, int out_size, void* d_ws, size_t ws_size,
                              hipStream_t stream) {
    (void)in_sizes; (void)n_in; (void)ws_size; (void)d_ws; (void)out_size;
    const float* data  = (const float*)d_in[0];
    const float* label = (const float*)d_in[1];
    const float* theta = (const float*)d_in[2];
    float* out = (float*)d_out;

    sgd_seq_kernel<<<1, 64, 0, stream>>>(data, label, theta, out);
}

// Round 4
// 6891.821 us; speedup vs baseline: 5.7297x; 5.7297x over previous
//
#include <hip/hip_runtime.h>
#include <hip/hip_cooperative_groups.h>

namespace cg = cooperative_groups;

#define F 1024
#define NTRAIN 32768
#define EPOCHS 2
#define STEP 0.01f
#define BB 512                  // scan block size
#define NBLK (NTRAIN / BB)      // 64 blocks per epoch
#define PHASES (EPOCHS * NBLK)  // 128 sequential phases
#define COOP_WGS 32

__device__ __forceinline__ float rdlane(float v, int lane) {
    return __uint_as_float(__builtin_amdgcn_readlane(__float_as_uint(v), (unsigned)lane));
}

// ---------------------------------------------------------------------------
// Kernel 1 (parallel, whole GPU): per-block Gram matrices G_b = X_b X_b^T.
// Triangular tiles (ti<=tj) + mirrored writes. fp32 vector FMA, LDS tiled.
// ---------------------------------------------------------------------------
__global__ __launch_bounds__(256) void gram_kernel(const float* __restrict__ X,
                                                   float* __restrict__ G)
{
    const int wg  = blockIdx.x;
    const int b   = wg / 36;
    int tij = wg % 36;
    int ti = 0;
    while (tij >= 8 - ti) { tij -= 8 - ti; ++ti; }
    const int tj = ti + tij;

    __shared__ __align__(16) float At[16][68];
    __shared__ __align__(16) float Bt[16][68];

    const int t  = threadIdx.x;
    const int tx = t & 15, ty = t >> 4;
    const int sr = t >> 2, sc = (t & 3) * 4;

    const float* Xa = X + (size_t)(b * BB + ti * 64) * F;
    const float* Xb = X + (size_t)(b * BB + tj * 64) * F;
    float* Gb = G + (size_t)b * BB * BB;

    float acc[4][4];
#pragma unroll
    for (int p = 0; p < 4; ++p)
#pragma unroll
        for (int q = 0; q < 4; ++q) acc[p][q] = 0.f;

    for (int kc = 0; kc < F; kc += 16) {
        float4 va = *(const float4*)(Xa + (size_t)sr * F + kc + sc);
        float4 vb = *(const float4*)(Xb + (size_t)sr * F + kc + sc);
        __syncthreads();
        At[sc + 0][sr] = va.x; At[sc + 1][sr] = va.y; At[sc + 2][sr] = va.z; At[sc + 3][sr] = va.w;
        Bt[sc + 0][sr] = vb.x; Bt[sc + 1][sr] = vb.y; Bt[sc + 2][sr] = vb.z; Bt[sc + 3][sr] = vb.w;
        __syncthreads();
#pragma unroll
        for (int k = 0; k < 16; ++k) {
            float4 a4 = *(const float4*)&At[k][ty * 4];
            float4 b4 = *(const float4*)&Bt[k][tx * 4];
            acc[0][0] = fmaf(a4.x, b4.x, acc[0][0]);
            acc[0][1] = fmaf(a4.x, b4.y, acc[0][1]);
            acc[0][2] = fmaf(a4.x, b4.z, acc[0][2]);
            acc[0][3] = fmaf(a4.x, b4.w, acc[0][3]);
            acc[1][0] = fmaf(a4.y, b4.x, acc[1][0]);
            acc[1][1] = fmaf(a4.y, b4.y, acc[1][1]);
            acc[1][2] = fmaf(a4.y, b4.z, acc[1][2]);
            acc[1][3] = fmaf(a4.y, b4.w, acc[1][3]);
            acc[2][0] = fmaf(a4.z, b4.x, acc[2][0]);
            acc[2][1] = fmaf(a4.z, b4.y, acc[2][1]);
            acc[2][2] = fmaf(a4.z, b4.z, acc[2][2]);
            acc[2][3] = fmaf(a4.z, b4.w, acc[2][3]);
            acc[3][0] = fmaf(a4.w, b4.x, acc[3][0]);
            acc[3][1] = fmaf(a4.w, b4.y, acc[3][1]);
            acc[3][2] = fmaf(a4.w, b4.z, acc[3][2]);
            acc[3][3] = fmaf(a4.w, b4.w, acc[3][3]);
        }
    }

#pragma unroll
    for (int p = 0; p < 4; ++p) {
        int i = ti * 64 + ty * 4 + p;
        float4 v = make_float4(acc[p][0], acc[p][1], acc[p][2], acc[p][3]);
        *(float4*)(Gb + (size_t)i * BB + tj * 64 + tx * 4) = v;
    }
    if (ti != tj) {
#pragma unroll
        for (int p = 0; p < 4; ++p)
#pragma unroll
            for (int q = 0; q < 4; ++q)
                Gb[(size_t)(tj * 64 + tx * 4 + q) * BB + ti * 64 + ty * 4 + p] = acc[p][q];
    }
}

// ---------------------------------------------------------------------------
// Kernel 2 (cooperative): the sequential part.
// Per phase: [WG0.wave0] 512-step scalar recurrence using G_blk
//            -> sync -> [WG0..15] rank-1 theta update
//            -> sync -> [all] s = X_next . theta   -> sync
// ---------------------------------------------------------------------------
__global__ __launch_bounds__(256) void sgd_coop(
    const float* __restrict__ X, const float* __restrict__ label,
    const float* __restrict__ theta0, float* __restrict__ out,
    const float* __restrict__ G, float* __restrict__ theta,
    float* __restrict__ sbuf, float* __restrict__ wbuf)
{
    cg::grid_group grid = cg::this_grid();
    const int tid = threadIdx.x;
    const int wg  = blockIdx.x;

    if (wg < 4) theta[wg * 256 + tid] = theta0[wg * 256 + tid];
    grid.sync();

    auto sgemv = [&](int blk) {
        const int wv = (wg << 2) | (tid >> 6);  // 0..127
        const int L  = tid & 63;
        const float4* th4 = (const float4*)theta;
        float4 t4[4];
#pragma unroll
        for (int m = 0; m < 4; ++m) t4[m] = th4[L + 64 * m];
        for (int rr = 0; rr < 4; ++rr) {
            const int r = wv * 4 + rr;
            const float4* xr = (const float4*)(X + (size_t)(blk * BB + r) * F);
            float acc = 0.f;
#pragma unroll
            for (int m = 0; m < 4; ++m) {
                float4 x4 = xr[L + 64 * m];
                acc = fmaf(x4.x, t4[m].x, acc);
                acc = fmaf(x4.y, t4[m].y, acc);
                acc = fmaf(x4.z, t4[m].z, acc);
                acc = fmaf(x4.w, t4[m].w, acc);
            }
#pragma unroll
            for (int off = 32; off > 0; off >>= 1)
                acc += __shfl_xor(acc, off, 64);
            if (L == 0) sbuf[r] = acc;
        }
    };

    sgemv(0);
    grid.sync();

    for (int p = 0; p < PHASES; ++p) {
        const int blk = p & (NBLK - 1);

        // ---- step 1: recurrence (one wave) ----
        if (wg == 0 && tid < 64) {
            const int L = tid;
            const float* Gb = G + (size_t)blk * BB * BB;
            // sample i <-> lane (i>>3), reg (i&7); zacc init = s
            const float4* s4 = (const float4*)sbuf;
            float4 z04 = s4[L * 2], z14 = s4[L * 2 + 1];
            float zac[8] = {z04.x, z04.y, z04.z, z04.w, z14.x, z14.y, z14.z, z14.w};
            const float4* y4 = (const float4*)(label + blk * BB);
            float4 ya = y4[L * 2], yb = y4[L * 2 + 1];
            float yv[8] = {ya.x, ya.y, ya.z, ya.w, yb.x, yb.y, yb.z, yb.w};

            // preload G rows 0..7 (lane L holds cols L*8..L*8+7)
            float4 gb0[8], gb1[8];
#pragma unroll
            for (int u = 0; u < 8; ++u) {
                const float4* gr = (const float4*)(Gb + (size_t)u * BB) + L * 2;
                gb0[u] = gr[0]; gb1[u] = gr[1];
            }

            for (int i8 = 0; i8 < 64; ++i8) {
                float wout[8];
#pragma unroll
                for (int u = 0; u < 8; ++u) {
                    float zi = rdlane(zac[u], i8);
                    float yi = rdlane(yv[u], i8);
                    // saturation-safe sigmoid: E=inf -> prob=0; E=0 -> prob=1
                    float E    = __builtin_amdgcn_exp2f(zi * -1.44269504088896f);
                    float prob = __builtin_amdgcn_rcpf(1.0f + E);
                    float wv   = STEP * (yi - prob);  // = -eta*(prob - y)
                    wout[u] = wv;
                    float4 g0 = gb0[u], g1 = gb1[u];
                    zac[0] = fmaf(wv, g0.x, zac[0]);
                    zac[1] = fmaf(wv, g0.y, zac[1]);
                    zac[2] = fmaf(wv, g0.z, zac[2]);
                    zac[3] = fmaf(wv, g0.w, zac[3]);
                    zac[4] = fmaf(wv, g1.x, zac[4]);
                    zac[5] = fmaf(wv, g1.y, zac[5]);
                    zac[6] = fmaf(wv, g1.z, zac[6]);
                    zac[7] = fmaf(wv, g1.w, zac[7]);
                    if (i8 < 63) {  // prefetch row (i8+1)*8+u
                        const float4* gr =
                            (const float4*)(Gb + (size_t)((i8 + 1) * 8 + u) * BB) + L * 2;
                        gb0[u] = gr[0]; gb1[u] = gr[1];
                    }
                }
                if (L == i8) {  // wout is wave-uniform; owner lane writes 8 w's
                    float4* wp = (float4*)(wbuf + i8 * 8);
                    wp[0] = make_float4(wout[0], wout[1], wout[2], wout[3]);
                    wp[1] = make_float4(wout[4], wout[5], wout[6], wout[7]);
                }
            }
        }
        grid.sync();

        // ---- step 2: theta += sum_i w_i * x_i  (16 WGs, 64 cols each) ----
        if (wg < 16) {
            __shared__ float red[4][64];
            const int j  = wg * 64 + (tid & 63);
            const int rg = tid >> 6;
            const float* Xb = X + (size_t)blk * BB * F;
            float acc = 0.f;
            for (int ii = 0; ii < 128; ++ii) {
                const int i = rg * 128 + ii;
                acc = fmaf(wbuf[i], Xb[(size_t)i * F + j], acc);
            }
            red[rg][tid & 63] = acc;
            __syncthreads();
            if (tid < 64) {
                float v = theta[j] + red[0][tid] + red[1][tid] + red[2][tid] + red[3][tid];
                theta[j] = v;
                if (p == PHASES - 1) out[j] = v;
            }
        }
        grid.sync();

        // ---- step 3: s = X_{next} . theta ----
        if (p + 1 < PHASES) sgemv((p + 1) & (NBLK - 1));
        grid.sync();
    }
}

// ---------------------------------------------------------------------------
// Fallback (R2): single-wave faithful sequential SGD (used if ws too small).
// ---------------------------------------------------------------------------
__global__ __launch_bounds__(64, 1) void sgd_seq_kernel(
    const float* __restrict__ data, const float* __restrict__ label,
    const float* __restrict__ theta_in, float* __restrict__ theta_out)
{
    const int lane = threadIdx.x;
    const float4* data4  = (const float4*)data;
    const float4* th4_in = (const float4*)theta_in;
    float4 th[4];
#pragma unroll
    for (int j = 0; j < 4; ++j) th[j] = th4_in[j * 64 + lane];
    float4 xv[4], xn[4];
#pragma unroll
    for (int j = 0; j < 4; ++j) xv[j] = data4[j * 64 + lane];
    float y = label[0];
    const int total = EPOCHS * NTRAIN;
    for (int it = 0; it < total; ++it) {
        int nn = it + 1;
        int nidx = (nn >= total) ? 0 : (nn & (NTRAIN - 1));
        const float4* xp = data4 + (size_t)nidx * (F / 4);
#pragma unroll
        for (int j = 0; j < 4; ++j) xn[j] = xp[j * 64 + lane];
        float ynext = label[nidx];
        float p0 = xv[0].x * th[0].x; p0 = fmaf(xv[0].y, th[0].y, p0);
        p0 = fmaf(xv[0].z, th[0].z, p0); p0 = fmaf(xv[0].w, th[0].w, p0);
        float p1 = xv[1].x * th[1].x; p1 = fmaf(xv[1].y, th[1].y, p1);
        p1 = fmaf(xv[1].z, th[1].z, p1); p1 = fmaf(xv[1].w, th[1].w, p1);
        float p2 = xv[2].x * th[2].x; p2 = fmaf(xv[2].y, th[2].y, p2);
        p2 = fmaf(xv[2].z, th[2].z, p2); p2 = fmaf(xv[2].w, th[2].w, p2);
        float p3 = xv[3].x * th[3].x; p3 = fmaf(xv[3].y, th[3].y, p3);
        p3 = fmaf(xv[3].z, th[3].z, p3); p3 = fmaf(xv[3].w, th[3].w, p3);
        float p = (p0 + p1) + (p2 + p3);
#pragma unroll
        for (int off = 32; off > 0; off >>= 1) p += __shfl_xor(p, off, 64);
        float e = __builtin_amdgcn_exp2f(-p * 1.44269504088896f);
        float prob = __builtin_amdgcn_rcpf(1.0f + e);
        float c = STEP * (prob - y);
#pragma unroll
        for (int j = 0; j < 4; ++j) {
            th[j].x = fmaf(-c, xv[j].x, th[j].x);
            th[j].y = fmaf(-c, xv[j].y, th[j].y);
            th[j].z = fmaf(-c, xv[j].z, th[j].z);
            th[j].w = fmaf(-c, xv[j].w, th[j].w);
        }
#pragma unroll
        for (int j = 0; j < 4; ++j) xv[j] = xn[j];
        y = ynext;
    }
    float4* out4 = (float4*)theta_out;
#pragma unroll
    for (int j = 0; j < 4; ++j) out4[j * 64 + lane] = th[j];
}

extern "C" void kernel_launch(void* const* d_in, const int* in_sizes, int n_in,
                              void* d_out, int out_size, void* d_ws, size_t ws_size,
                              hipStream_t stream) {
    (void)in_sizes; (void)n_in; (void)out_size;
    const float* X      = (const float*)d_in[0];
    const float* label  = (const float*)d_in[1];
    const float* theta0 = (const float*)d_in[2];
    float* out = (float*)d_out;

    const size_t gsz  = (size_t)NBLK * BB * BB;          // 16,777,216 floats
    const size_t need = (gsz + F + BB + BB) * sizeof(float);

    if (ws_size < need) {  // workspace too small for Gram path: faithful fallback
        sgd_seq_kernel<<<1, 64, 0, stream>>>(X, label, theta0, out);
        return;
    }

    float* G     = (float*)d_ws;
    float* theta = G + gsz;
    float* sbuf  = theta + F;
    float* wbuf  = sbuf + BB;

    gram_kernel<<<NBLK * 36, 256, 0, stream>>>(X, G);

    void* args[] = {(void*)&X, (void*)&label, (void*)&theta0, (void*)&out,
                    (void*)&G, (void*)&theta, (void*)&sbuf, (void*)&wbuf};
    hipLaunchCooperativeKernel((void*)sgd_coop, dim3(COOP_WGS), dim3(256),
                               args, 0, stream);
}

// Round 5
// 6713.428 us; speedup vs baseline: 5.8820x; 1.0266x over previous
//
#include <hip/hip_runtime.h>
#include <hip/hip_cooperative_groups.h>

namespace cg = cooperative_groups;

#define F 1024
#define NTRAIN 32768
#define EPOCHS 2
#define STEP 0.01f
#define BB 512                  // scan block size
#define NBLK (NTRAIN / BB)      // 64 blocks per epoch
#define PHASES (EPOCHS * NBLK)  // 128 sequential phases
#define COOP_WGS 32

#define NL2E 1.4426950408889634f          // log2(e)
#define C1K  0.014426950408889634f        // STEP * log2(e)
#define NLN2 0.69314718055994531f         // ln(2)

__device__ __forceinline__ float rdlane(float v, int lane) {
    return __uint_as_float(__builtin_amdgcn_readlane(__float_as_uint(v), (unsigned)lane));
}

// ---------------------------------------------------------------------------
// Gram kernel: per block b, tiles_per_b==36 -> G_b = X_b X_b^T (triangular +
// mirror). tiles_per_b==100 -> additionally C_b = X_{b+1} X_b^T (64 full
// tiles, rows from next block, cols from current block).
// ---------------------------------------------------------------------------
__global__ __launch_bounds__(256) void gram_kernel(const float* __restrict__ X,
                                                   float* __restrict__ G,
                                                   float* __restrict__ C,
                                                   int tiles_per_b)
{
    const int wg  = blockIdx.x;
    const int b   = wg / tiles_per_b;
    int rem = wg % tiles_per_b;

    int ti, tj;
    bool isC = (rem >= 36);
    if (!isC) {
        int tij = rem; ti = 0;
        while (tij >= 8 - ti) { tij -= 8 - ti; ++ti; }
        tj = ti + tij;
    } else {
        rem -= 36; ti = rem >> 3; tj = rem & 7;
    }

    __shared__ __align__(16) float At[16][68];
    __shared__ __align__(16) float Bt[16][68];

    const int t  = threadIdx.x;
    const int tx = t & 15, ty = t >> 4;
    const int sr = t >> 2, sc = (t & 3) * 4;

    const int rowBlk = isC ? ((b + 1) & (NBLK - 1)) : b;
    const float* Xa = X + (size_t)(rowBlk * BB + ti * 64) * F;
    const float* Xb = X + (size_t)(b * BB + tj * 64) * F;
    float* Ob = (isC ? C : G) + (size_t)b * BB * BB;

    float acc[4][4];
#pragma unroll
    for (int p = 0; p < 4; ++p)
#pragma unroll
        for (int q = 0; q < 4; ++q) acc[p][q] = 0.f;

    for (int kc = 0; kc < F; kc += 16) {
        float4 va = *(const float4*)(Xa + (size_t)sr * F + kc + sc);
        float4 vb = *(const float4*)(Xb + (size_t)sr * F + kc + sc);
        __syncthreads();
        At[sc + 0][sr] = va.x; At[sc + 1][sr] = va.y; At[sc + 2][sr] = va.z; At[sc + 3][sr] = va.w;
        Bt[sc + 0][sr] = vb.x; Bt[sc + 1][sr] = vb.y; Bt[sc + 2][sr] = vb.z; Bt[sc + 3][sr] = vb.w;
        __syncthreads();
#pragma unroll
        for (int k = 0; k < 16; ++k) {
            float4 a4 = *(const float4*)&At[k][ty * 4];
            float4 b4 = *(const float4*)&Bt[k][tx * 4];
            acc[0][0] = fmaf(a4.x, b4.x, acc[0][0]);
            acc[0][1] = fmaf(a4.x, b4.y, acc[0][1]);
            acc[0][2] = fmaf(a4.x, b4.z, acc[0][2]);
            acc[0][3] = fmaf(a4.x, b4.w, acc[0][3]);
            acc[1][0] = fmaf(a4.y, b4.x, acc[1][0]);
            acc[1][1] = fmaf(a4.y, b4.y, acc[1][1]);
            acc[1][2] = fmaf(a4.y, b4.z, acc[1][2]);
            acc[1][3] = fmaf(a4.y, b4.w, acc[1][3]);
            acc[2][0] = fmaf(a4.z, b4.x, acc[2][0]);
            acc[2][1] = fmaf(a4.z, b4.y, acc[2][1]);
            acc[2][2] = fmaf(a4.z, b4.z, acc[2][2]);
            acc[2][3] = fmaf(a4.z, b4.w, acc[2][3]);
            acc[3][0] = fmaf(a4.w, b4.x, acc[3][0]);
            acc[3][1] = fmaf(a4.w, b4.y, acc[3][1]);
            acc[3][2] = fmaf(a4.w, b4.z, acc[3][2]);
            acc[3][3] = fmaf(a4.w, b4.w, acc[3][3]);
        }
    }

#pragma unroll
    for (int p = 0; p < 4; ++p) {
        int i = ti * 64 + ty * 4 + p;
        float4 v = make_float4(acc[p][0], acc[p][1], acc[p][2], acc[p][3]);
        *(float4*)(Ob + (size_t)i * BB + tj * 64 + tx * 4) = v;
    }
    if (!isC && ti != tj) {
#pragma unroll
        for (int p = 0; p < 4; ++p)
#pragma unroll
            for (int q = 0; q < 4; ++q)
                Ob[(size_t)(tj * 64 + tx * 4 + q) * BB + ti * 64 + ty * 4 + p] = acc[p][q];
    }
}

// ---------------------------------------------------------------------------
// Cooperative kernel v2 (overlap): per phase
//   slot1: [WG0.wave0: recurrence] || [WG1..31: spre = X_{b+1} . theta]
//   sync
//   slot2: [WG0..15: theta += X_b^T w] || [WG16..31: sbuf = spre + C_b . w]
//   sync
// ---------------------------------------------------------------------------
__global__ __launch_bounds__(256) void sgd_coop2(
    const float* __restrict__ X, const float* __restrict__ label,
    const float* __restrict__ theta0, float* __restrict__ out,
    const float* __restrict__ G, const float* __restrict__ C,
    float* __restrict__ theta, float* __restrict__ sbuf,
    float* __restrict__ spre, float* __restrict__ wbuf)
{
    cg::grid_group grid = cg::this_grid();
    const int tid = threadIdx.x;
    const int wg  = blockIdx.x;

    if (wg < 4) theta[wg * 256 + tid] = theta0[wg * 256 + tid];
    grid.sync();

    // initial s_0 = X_0 . theta0 (all 32 WGs)
    {
        const int wv = (wg << 2) | (tid >> 6);  // 0..127
        const int L  = tid & 63;
        const float4* th4 = (const float4*)theta;
        float4 t4[4];
#pragma unroll
        for (int m = 0; m < 4; ++m) t4[m] = th4[L + 64 * m];
        for (int rr = 0; rr < 4; ++rr) {
            const int r = wv * 4 + rr;
            const float4* xr = (const float4*)(X + (size_t)r * F);
            float acc = 0.f;
#pragma unroll
            for (int m = 0; m < 4; ++m) {
                float4 x4 = xr[L + 64 * m];
                acc = fmaf(x4.x, t4[m].x, acc);
                acc = fmaf(x4.y, t4[m].y, acc);
                acc = fmaf(x4.z, t4[m].z, acc);
                acc = fmaf(x4.w, t4[m].w, acc);
            }
#pragma unroll
            for (int off = 32; off > 0; off >>= 1)
                acc += __shfl_xor(acc, off, 64);
            if (L == 0) sbuf[r] = acc;
        }
    }
    grid.sync();

    for (int p = 0; p < PHASES; ++p) {
        const int blk = p & (NBLK - 1);

        // ================= slot 1 =================
        if (wg == 0) {
            if (tid < 64) {
                const int L = tid;
                const float* Gb = G + (size_t)blk * BB * BB;
                // z kept in scaled domain: zac = -log2(e) * z
                const float4* s4 = (const float4*)sbuf;
                float4 z04 = s4[L * 2], z14 = s4[L * 2 + 1];
                float zac[8] = {-NL2E * z04.x, -NL2E * z04.y, -NL2E * z04.z, -NL2E * z04.w,
                                -NL2E * z14.x, -NL2E * z14.y, -NL2E * z14.z, -NL2E * z14.w};
                const float4* y4 = (const float4*)(label + blk * BB);
                float4 ya = y4[L * 2], yb = y4[L * 2 + 1];
                // wv2 = -log2e * w_true = C1K*prob - C1K*y ; c2 = -C1K*y
                float c2[8] = {-C1K * ya.x, -C1K * ya.y, -C1K * ya.z, -C1K * ya.w,
                               -C1K * yb.x, -C1K * yb.y, -C1K * yb.z, -C1K * yb.w};

                float4 gb0[8], gb1[8];
#pragma unroll
                for (int u = 0; u < 8; ++u) {
                    const float4* gr = (const float4*)(Gb + (size_t)u * BB) + L * 2;
                    gb0[u] = gr[0]; gb1[u] = gr[1];
                }

                for (int i8 = 0; i8 < 64; ++i8) {
                    float wout[8];
#pragma unroll
                    for (int u = 0; u < 8; ++u) {
                        float zs = rdlane(zac[u], i8);   // -log2e * z_i
                        float cc = rdlane(c2[u], i8);
                        float E    = __builtin_amdgcn_exp2f(zs);          // exp(-z)
                        float prob = __builtin_amdgcn_rcpf(1.0f + E);     // sigmoid
                        float wv2  = fmaf(C1K, prob, cc);                 // scaled w
                        wout[u] = wv2 * -NLN2;                            // true w
                        float ga[8] = {gb0[u].x, gb0[u].y, gb0[u].z, gb0[u].w,
                                       gb1[u].x, gb1[u].y, gb1[u].z, gb1[u].w};
                        // critical-path fma (next sample's accumulator) first
#pragma unroll
                        for (int jj = 0; jj < 8; ++jj) {
                            int j = (u + 1 + jj) & 7;
                            zac[j] = fmaf(wv2, ga[j], zac[j]);
                        }
                        if (i8 < 63) {
                            const float4* gr =
                                (const float4*)(Gb + (size_t)((i8 + 1) * 8 + u) * BB) + L * 2;
                            gb0[u] = gr[0]; gb1[u] = gr[1];
                        }
                    }
                    if (L == i8) {
                        float4* wp = (float4*)(wbuf + i8 * 8);
                        wp[0] = make_float4(wout[0], wout[1], wout[2], wout[3]);
                        wp[1] = make_float4(wout[4], wout[5], wout[6], wout[7]);
                    }
                }
            }
        } else if (p + 1 < PHASES) {
            // spre = X_{next} . theta   (124 waves)
            const int w = (wg - 1) * 4 + (tid >> 6);  // 0..123
            const int L = tid & 63;
            const int nblk = (p + 1) & (NBLK - 1);
            const float4* th4 = (const float4*)theta;
            float4 t4[4];
#pragma unroll
            for (int m = 0; m < 4; ++m) t4[m] = th4[L + 64 * m];
            for (int r = w; r < BB; r += 124) {
                const float4* xr = (const float4*)(X + (size_t)(nblk * BB + r) * F);
                float acc = 0.f;
#pragma unroll
                for (int m = 0; m < 4; ++m) {
                    float4 x4 = xr[L + 64 * m];
                    acc = fmaf(x4.x, t4[m].x, acc);
                    acc = fmaf(x4.y, t4[m].y, acc);
                    acc = fmaf(x4.z, t4[m].z, acc);
                    acc = fmaf(x4.w, t4[m].w, acc);
                }
#pragma unroll
                for (int off = 32; off > 0; off >>= 1)
                    acc += __shfl_xor(acc, off, 64);
                if (L == 0) spre[r] = acc;
            }
        }
        grid.sync();

        // ================= slot 2 =================
        if (wg < 16) {
            // theta += sum_i w_i x_i
            __shared__ float red[4][64];
            const int j  = wg * 64 + (tid & 63);
            const int rg = tid >> 6;
            const float* Xb = X + (size_t)blk * BB * F;
            float acc = 0.f;
            for (int ii = 0; ii < 128; ++ii) {
                const int i = rg * 128 + ii;
                acc = fmaf(wbuf[i], Xb[(size_t)i * F + j], acc);
            }
            red[rg][tid & 63] = acc;
            __syncthreads();
            if (tid < 64) {
                float v = theta[j] + red[0][tid] + red[1][tid] + red[2][tid] + red[3][tid];
                theta[j] = v;
                if (p == PHASES - 1) out[j] = v;
            }
        } else if (p + 1 < PHASES) {
            // sbuf = spre + C_blk . w    (64 waves, 8 rows each)
            const int w2 = (wg - 16) * 4 + (tid >> 6);  // 0..63
            const int L  = tid & 63;
            const float* Cb = C + (size_t)blk * BB * BB;
            const float4* w4 = (const float4*)wbuf;
            float4 wa = w4[L * 2], wb4 = w4[L * 2 + 1];
            for (int rr = 0; rr < 8; ++rr) {
                const int r = w2 * 8 + rr;
                const float4* cr = (const float4*)(Cb + (size_t)r * BB) + L * 2;
                float4 c0 = cr[0], c1r = cr[1];
                float acc = c0.x * wa.x;
                acc = fmaf(c0.y, wa.y, acc);
                acc = fmaf(c0.z, wa.z, acc);
                acc = fmaf(c0.w, wa.w, acc);
                acc = fmaf(c1r.x, wb4.x, acc);
                acc = fmaf(c1r.y, wb4.y, acc);
                acc = fmaf(c1r.z, wb4.z, acc);
                acc = fmaf(c1r.w, wb4.w, acc);
#pragma unroll
                for (int off = 32; off > 0; off >>= 1)
                    acc += __shfl_xor(acc, off, 64);
                if (L == 0) sbuf[r] = spre[r] + acc;
            }
        }
        grid.sync();
    }
}

// ---------------------------------------------------------------------------
// R4 cooperative kernel (fallback if ws too small for C): 3-sync structure.
// ---------------------------------------------------------------------------
__global__ __launch_bounds__(256) void sgd_coop(
    const float* __restrict__ X, const float* __restrict__ label,
    const float* __restrict__ theta0, float* __restrict__ out,
    const float* __restrict__ G, float* __restrict__ theta,
    float* __restrict__ sbuf, float* __restrict__ wbuf)
{
    cg::grid_group grid = cg::this_grid();
    const int tid = threadIdx.x;
    const int wg  = blockIdx.x;

    if (wg < 4) theta[wg * 256 + tid] = theta0[wg * 256 + tid];
    grid.sync();

    auto sgemv = [&](int blk) {
        const int wv = (wg << 2) | (tid >> 6);
        const int L  = tid & 63;
        const float4* th4 = (const float4*)theta;
        float4 t4[4];
#pragma unroll
        for (int m = 0; m < 4; ++m) t4[m] = th4[L + 64 * m];
        for (int rr = 0; rr < 4; ++rr) {
            const int r = wv * 4 + rr;
            const float4* xr = (const float4*)(X + (size_t)(blk * BB + r) * F);
            float acc = 0.f;
#pragma unroll
            for (int m = 0; m < 4; ++m) {
                float4 x4 = xr[L + 64 * m];
                acc = fmaf(x4.x, t4[m].x, acc);
                acc = fmaf(x4.y, t4[m].y, acc);
                acc = fmaf(x4.z, t4[m].z, acc);
                acc = fmaf(x4.w, t4[m].w, acc);
            }
#pragma unroll
            for (int off = 32; off > 0; off >>= 1)
                acc += __shfl_xor(acc, off, 64);
            if (L == 0) sbuf[r] = acc;
        }
    };

    sgemv(0);
    grid.sync();

    for (int p = 0; p < PHASES; ++p) {
        const int blk = p & (NBLK - 1);
        if (wg == 0 && tid < 64) {
            const int L = tid;
            const float* Gb = G + (size_t)blk * BB * BB;
            const float4* s4 = (const float4*)sbuf;
            float4 z04 = s4[L * 2], z14 = s4[L * 2 + 1];
            float zac[8] = {z04.x, z04.y, z04.z, z04.w, z14.x, z14.y, z14.z, z14.w};
            const float4* y4 = (const float4*)(label + blk * BB);
            float4 ya = y4[L * 2], yb = y4[L * 2 + 1];
            float yv[8] = {ya.x, ya.y, ya.z, ya.w, yb.x, yb.y, yb.z, yb.w};
            float4 gb0[8], gb1[8];
#pragma unroll
            for (int u = 0; u < 8; ++u) {
                const float4* gr = (const float4*)(Gb + (size_t)u * BB) + L * 2;
                gb0[u] = gr[0]; gb1[u] = gr[1];
            }
            for (int i8 = 0; i8 < 64; ++i8) {
                float wout[8];
#pragma unroll
                for (int u = 0; u < 8; ++u) {
                    float zi = rdlane(zac[u], i8);
                    float yi = rdlane(yv[u], i8);
                    float E    = __builtin_amdgcn_exp2f(zi * -NL2E);
                    float prob = __builtin_amdgcn_rcpf(1.0f + E);
                    float wv   = STEP * (yi - prob);
                    wout[u] = wv;
                    float4 g0 = gb0[u], g1 = gb1[u];
                    zac[0] = fmaf(wv, g0.x, zac[0]);
                    zac[1] = fmaf(wv, g0.y, zac[1]);
                    zac[2] = fmaf(wv, g0.z, zac[2]);
                    zac[3] = fmaf(wv, g0.w, zac[3]);
                    zac[4] = fmaf(wv, g1.x, zac[4]);
                    zac[5] = fmaf(wv, g1.y, zac[5]);
                    zac[6] = fmaf(wv, g1.z, zac[6]);
                    zac[7] = fmaf(wv, g1.w, zac[7]);
                    if (i8 < 63) {
                        const float4* gr =
                            (const float4*)(Gb + (size_t)((i8 + 1) * 8 + u) * BB) + L * 2;
                        gb0[u] = gr[0]; gb1[u] = gr[1];
                    }
                }
                if (L == i8) {
                    float4* wp = (float4*)(wbuf + i8 * 8);
                    wp[0] = make_float4(wout[0], wout[1], wout[2], wout[3]);
                    wp[1] = make_float4(wout[4], wout[5], wout[6], wout[7]);
                }
            }
        }
        grid.sync();

        if (wg < 16) {
            __shared__ float red[4][64];
            const int j  = wg * 64 + (tid & 63);
            const int rg = tid >> 6;
            const float* Xb = X + (size_t)blk * BB * F;
            float acc = 0.f;
            for (int ii = 0; ii < 128; ++ii) {
                const int i = rg * 128 + ii;
                acc = fmaf(wbuf[i], Xb[(size_t)i * F + j], acc);
            }
            red[rg][tid & 63] = acc;
            __syncthreads();
            if (tid < 64) {
                float v = theta[j] + red[0][tid] + red[1][tid] + red[2][tid] + red[3][tid];
                theta[j] = v;
                if (p == PHASES - 1) out[j] = v;
            }
        }
        grid.sync();

        if (p + 1 < PHASES) sgemv((p + 1) & (NBLK - 1));
        grid.sync();
    }
}

// ---------------------------------------------------------------------------
// Last-resort fallback: single-wave faithful sequential SGD.
// ---------------------------------------------------------------------------
__global__ __launch_bounds__(64, 1) void sgd_seq_kernel(
    const float* __restrict__ data, const float* __restrict__ label,
    const float* __restrict__ theta_in, float* __restrict__ theta_out)
{
    const int lane = threadIdx.x;
    const float4* data4  = (const float4*)data;
    const float4* th4_in = (const float4*)theta_in;
    float4 th[4];
#pragma unroll
    for (int j = 0; j < 4; ++j) th[j] = th4_in[j * 64 + lane];
    float4 xv[4], xn[4];
#pragma unroll
    for (int j = 0; j < 4; ++j) xv[j] = data4[j * 64 + lane];
    float y = label[0];
    const int total = EPOCHS * NTRAIN;
    for (int it = 0; it < total; ++it) {
        int nn = it + 1;
        int nidx = (nn >= total) ? 0 : (nn & (NTRAIN - 1));
        const float4* xp = data4 + (size_t)nidx * (F / 4);
#pragma unroll
        for (int j = 0; j < 4; ++j) xn[j] = xp[j * 64 + lane];
        float ynext = label[nidx];
        float p0 = xv[0].x * th[0].x; p0 = fmaf(xv[0].y, th[0].y, p0);
        p0 = fmaf(xv[0].z, th[0].z, p0); p0 = fmaf(xv[0].w, th[0].w, p0);
        float p1 = xv[1].x * th[1].x; p1 = fmaf(xv[1].y, th[1].y, p1);
        p1 = fmaf(xv[1].z, th[1].z, p1); p1 = fmaf(xv[1].w, th[1].w, p1);
        float p2 = xv[2].x * th[2].x; p2 = fmaf(xv[2].y, th[2].y, p2);
        p2 = fmaf(xv[2].z, th[2].z, p2); p2 = fmaf(xv[2].w, th[2].w, p2);
        float p3 = xv[3].x * th[3].x; p3 = fmaf(xv[3].y, th[3].y, p3);
        p3 = fmaf(xv[3].z, th[3].z, p3); p3 = fmaf(xv[3].w, th[3].w, p3);
        float p = (p0 + p1) + (p2 + p3);
#pragma unroll
        for (int off = 32; off > 0; off >>= 1) p += __shfl_xor(p, off, 64);
        float e = __builtin_amdgcn_exp2f(-p * NL2E);
        float prob = __builtin_amdgcn_rcpf(1.0f + e);
        float c = STEP * (prob - y);
#pragma unroll
        for (int j = 0; j < 4; ++j) {
            th[j].x = fmaf(-c, xv[j].x, th[j].x);
            th[j].y = fmaf(-c, xv[j].y, th[j].y);
            th[j].z = fmaf(-c, xv[j].z, th[j].z);
            th[j].w = fmaf(-c, xv[j].w, th[j].w);
        }
#pragma unroll
        for (int j = 0; j < 4; ++j) xv[j] = xn[j];
        y = ynext;
    }
    float4* out4 = (float4*)theta_out;
#pragma unroll
    for (int j = 0; j < 4; ++j) out4[j * 64 + lane] = th[j];
}

extern "C" void kernel_launch(void* const* d_in, const int* in_sizes, int n_in,
                              void* d_out, int out_size, void* d_ws, size_t ws_size,
                              hipStream_t stream) {
    (void)in_sizes; (void)n_in; (void)out_size;
    const float* X      = (const float*)d_in[0];
    const float* label  = (const float*)d_in[1];
    const float* theta0 = (const float*)d_in[2];
    float* out = (float*)d_out;

    const size_t gsz   = (size_t)NBLK * BB * BB;  // 16,777,216 floats (64 MB)
    const size_t need2 = (2 * gsz + F + 3 * BB) * sizeof(float);  // ~128 MB
    const size_t need1 = (gsz + F + 2 * BB) * sizeof(float);      // ~64 MB

    if (ws_size >= need2) {
        float* G     = (float*)d_ws;
        float* C     = G + gsz;
        float* theta = C + gsz;
        float* sbuf  = theta + F;
        float* spre  = sbuf + BB;
        float* wbuf  = spre + BB;
        int tiles = 100;
        gram_kernel<<<NBLK * 100, 256, 0, stream>>>(X, G, C, tiles);
        const float* Gc = G; const float* Cc = C;
        void* args[] = {(void*)&X, (void*)&label, (void*)&theta0, (void*)&out,
                        (void*)&Gc, (void*)&Cc, (void*)&theta, (void*)&sbuf,
                        (void*)&spre, (void*)&wbuf};
        hipLaunchCooperativeKernel((void*)sgd_coop2, dim3(COOP_WGS), dim3(256),
                                   args, 0, stream);
    } else if (ws_size >= need1) {
        float* G     = (float*)d_ws;
        float* theta = G + gsz;
        float* sbuf  = theta + F;
        float* wbuf  = sbuf + BB;
        int tiles = 36;
        gram_kernel<<<NBLK * 36, 256, 0, stream>>>(X, G, nullptr, tiles);
        void* args[] = {(void*)&X, (void*)&label, (void*)&theta0, (void*)&out,
                        (void*)&G, (void*)&theta, (void*)&sbuf, (void*)&wbuf};
        hipLaunchCooperativeKernel((void*)sgd_coop, dim3(COOP_WGS), dim3(256),
                                   args, 0, stream);
    } else {
        sgd_seq_kernel<<<1, 64, 0, stream>>>(X, label, theta0, out);
    }
}